// Round 3
// baseline (190.936 us; speedup 1.0000x reference)
//
#include <hip/hip_runtime.h>

#define N_SP 16384
#define C_DIM 128
#define K_DIM 32
#define NBX   32      // blocks along n
#define TILES 4       // 128-n tiles per block; NBX*TILES*128 == N_SP

typedef short short8 __attribute__((ext_vector_type(8)));
typedef float f32x16 __attribute__((ext_vector_type(16)));

__device__ __forceinline__ unsigned short f2bf(float f){
    return (unsigned short)((__float_as_uint(f) + 0x8000u) >> 16);  // cheap RN
}

// swizzled index into a [row][128] ushort LDS tile: XOR bits 3..5 of n with row&7
#define SWZ(row, n) ((((row) * 128) + (n)) ^ (((row) & 7) << 3))

__device__ __forceinline__ void loadg(float (&buf)[8], const float* __restrict__ xp, int g){
#pragma unroll
    for (int j = 0; j < 8; ++j) buf[j] = xp[(g * 8 + j) * N_SP];
}

__device__ __forceinline__ void consume(const float (&buf)[8], int g, int t,
                                        unsigned short* xs,
                                        const float* __restrict__ cwt2,
                                        float& x2, float (&xc)[K_DIM]){
#pragma unroll
    for (int j = 0; j < 8; ++j){
        const int c  = g * 8 + j;
        const float xv = buf[j];
        x2 = fmaf(xv, xv, x2);
        xs[SWZ(c, t)] = f2bf(xv);
        const float* cwc = cwt2 + (c << 5);   // wave-uniform -> scalar loads
#pragma unroll
        for (int k = 0; k < K_DIM; ++k)
            xc[k] = fmaf(xv, cwc[k], xc[k]);
    }
}

__global__ __launch_bounds__(128) void enc_main(
    const float* __restrict__ x,      // [B][C][N]
    const float* __restrict__ cwt2,   // [C][K] = -2*scale[k]*cw[k][c]
    const float* __restrict__ scale,  // [K]
    const float* __restrict__ sc2,    // [K] = scale[k]*||cw_k||^2
    float* __restrict__ wxacc,        // [B][K][C] (zeroed)
    float* __restrict__ wsacc)        // [B][K]    (zeroed)
{
    __shared__ unsigned short xs[C_DIM * 128];   // bf16 x[c][n'] swizzled (32 KB)
    __shared__ unsigned short aws[K_DIM * 128];  // bf16 aw[k][n'] swizzled (8 KB)

    const int t   = threadIdx.x;     // 0..127
    const int b   = blockIdx.y;
    const int l   = t & 63;
    const int w   = t >> 6;          // wave id (0..1)
    const int hi  = l >> 5;
    const int l31 = l & 31;

    const float* xb = x + (size_t)b * C_DIM * N_SP;

    f32x16 acc0, acc1, accS;
#pragma unroll
    for (int i = 0; i < 16; ++i){ acc0[i] = 0.f; acc1[i] = 0.f; accS[i] = 0.f; }

    short8 ones;
#pragma unroll
    for (int i = 0; i < 8; ++i) ones[i] = (short)0x3F80;  // bf16 1.0

    // wave w owns output c-tiles 2w and 2w+1
    const int c_a = (2 * w) * 32 + l31;
    const int c_b = c_a + 32;

    for (int tile = 0; tile < TILES; ++tile){
        const int n0 = blockIdx.x * (TILES * 128) + tile * 128;
        const float* xp = xb + n0 + t;

        // prologue loads: issued BEFORE the barrier (global only, no LDS touch)
        // -> overlap previous tile's MFMA phase
        float bA[8], bB[8], bC[8], bD[8];
        loadg(bA, xp, 0); loadg(bB, xp, 1); loadg(bC, xp, 2); loadg(bD, xp, 3);

        __syncthreads();   // xs/aws now safe to overwrite (prev MFMA readers done)

        float xc[K_DIM];
#pragma unroll
        for (int k = 0; k < K_DIM; ++k) xc[k] = 0.f;
        float x2 = 0.f;

        // ---- phase 1: depth-4 pipelined stream (24-32 loads in flight) ----
#pragma unroll 1
        for (int gq = 0; gq < 3; ++gq){
            const int g0 = gq * 4;
            consume(bA, g0 + 0, t, xs, cwt2, x2, xc); loadg(bA, xp, g0 + 4);
            consume(bB, g0 + 1, t, xs, cwt2, x2, xc); loadg(bB, xp, g0 + 5);
            consume(bC, g0 + 2, t, xs, cwt2, x2, xc); loadg(bC, xp, g0 + 6);
            consume(bD, g0 + 3, t, xs, cwt2, x2, xc); loadg(bD, xp, g0 + 7);
        }
        consume(bA, 12, t, xs, cwt2, x2, xc);
        consume(bB, 13, t, xs, cwt2, x2, xc);
        consume(bC, 14, t, xs, cwt2, x2, xc);
        consume(bD, 15, t, xs, cwt2, x2, xc);

        // ---- phase 2: per-thread softmax over k ----
        float m = -3.4e38f;
#pragma unroll
        for (int k = 0; k < K_DIM; ++k){
            float s = fmaf(scale[k], x2, xc[k] + sc2[k]);  // scale*(x2 - 2x.cw + c2)
            xc[k] = s;
            m = fmaxf(m, s);
        }
        float sum = 0.f;
#pragma unroll
        for (int k = 0; k < K_DIM; ++k){
            float p = __expf(xc[k] - m);
            xc[k] = p;
            sum += p;
        }
        float r = 1.f / sum;
#pragma unroll
        for (int k = 0; k < K_DIM; ++k)
            aws[SWZ(k, t)] = f2bf(xc[k] * r);

        __syncthreads();

        // ---- phase 3: wx[k][c] += aw[k][n] * x[n][c] via MFMA (acc across tiles) ----
#pragma unroll
        for (int nch = 0; nch < 8; ++nch){
            const int n8 = nch * 16 + hi * 8;   // K-dim (n) elems for this lane
            short8 af  = *(const short8*)(const void*)&aws[SWZ(l31, n8)];
            short8 bf0 = *(const short8*)(const void*)&xs[SWZ(c_a, n8)];
            short8 bf1 = *(const short8*)(const void*)&xs[SWZ(c_b, n8)];
            acc0 = __builtin_amdgcn_mfma_f32_32x32x16_bf16(af, bf0, acc0, 0, 0, 0);
            acc1 = __builtin_amdgcn_mfma_f32_32x32x16_bf16(af, bf1, acc1, 0, 0, 0);
            if (w == 0)
                accS = __builtin_amdgcn_mfma_f32_32x32x16_bf16(af, ones, accS, 0, 0, 0);
        }
    }

    // ---- epilogue: atomic-reduce block partials to global ----
    float* wxb = wxacc + (size_t)b * K_DIM * C_DIM;
#pragma unroll
    for (int rg = 0; rg < 16; ++rg){
        const int row = (rg & 3) + 8 * (rg >> 2) + 4 * hi;  // verified D layout
        atomicAdd(&wxb[row * C_DIM + c_a], acc0[rg]);
        atomicAdd(&wxb[row * C_DIM + c_b], acc1[rg]);
    }
    if (w == 0 && l31 == 0){
#pragma unroll
        for (int rg = 0; rg < 16; ++rg){
            const int row = (rg & 3) + 8 * (rg >> 2) + 4 * hi;
            atomicAdd(&wsacc[b * K_DIM + row], accS[rg]);
        }
    }
}

__global__ void enc_zero(float* __restrict__ p, int n){
    const int i = blockIdx.x * 256 + threadIdx.x;
    if (i < n) p[i] = 0.f;
}

__global__ void enc_prep(const float* __restrict__ cw, const float* __restrict__ scale,
                         float* __restrict__ cwt2, float* __restrict__ sc2){
    const int t = threadIdx.x;  // 128 threads; t = c
    for (int k = 0; k < K_DIM; ++k)
        cwt2[t * K_DIM + k] = -2.f * scale[k] * cw[k * C_DIM + t];
    if (t < K_DIM){
        float s = 0.f;
        for (int c = 0; c < C_DIM; ++c){
            float v = cw[t * C_DIM + c];
            s = fmaf(v, v, s);
        }
        sc2[t] = scale[t] * s;
    }
}

__global__ void enc_final(const float* __restrict__ wxacc, const float* __restrict__ wsacc,
                          const float* __restrict__ cw, float* __restrict__ out){
    const int i  = blockIdx.x * 256 + threadIdx.x;  // B*K*C = 131072
    const int c  = i & (C_DIM - 1);
    const int kk = (i >> 7) & (K_DIM - 1);
    const int bk = i >> 7;
    out[i] = wxacc[i] - wsacc[bk] * cw[kk * C_DIM + c];
}

extern "C" void kernel_launch(void* const* d_in, const int* in_sizes, int n_in,
                              void* d_out, int out_size, void* d_ws, size_t ws_size,
                              hipStream_t stream){
    (void)in_sizes; (void)n_in; (void)out_size; (void)ws_size;
    const float* x     = (const float*)d_in[0];
    const float* cw    = (const float*)d_in[1];
    const float* scale = (const float*)d_in[2];
    float* out = (float*)d_out;

    float* wxacc = (float*)d_ws;                 // 32*32*128 f32
    float* wsacc = wxacc + 32 * 32 * 128;        // 32*32
    float* cwt2  = wsacc + 32 * 32;              // 128*32
    float* sc2   = cwt2 + 128 * 32;              // 32

    const int nz = 32 * 32 * 128 + 32 * 32;
    enc_zero<<<(nz + 255) / 256, 256, 0, stream>>>(wxacc, nz);
    enc_prep<<<1, 128, 0, stream>>>(cw, scale, cwt2, sc2);
    enc_main<<<dim3(NBX, 32), 128, 0, stream>>>(x, cwt2, scale, sc2, wxacc, wsacc);
    enc_final<<<512, 256, 0, stream>>>(wxacc, wsacc, cw, out);
}

// Round 4
// 144.338 us; speedup vs baseline: 1.3228x; 1.3228x over previous
//
#include <hip/hip_runtime.h>

#define N_SP 16384
#define C_DIM 128
#define K_DIM 32
#define NBX   64     // blocks along n
#define TILEN 64     // n per tile
#define TILES 4      // tiles per block; NBX*TILES*TILEN == N_SP

typedef short short8 __attribute__((ext_vector_type(8)));
typedef float f32x16 __attribute__((ext_vector_type(16)));

__device__ __forceinline__ unsigned short f2bf(float f){
    return (unsigned short)((__float_as_uint(f) + 0x8000u) >> 16);  // cheap RN
}

// swizzled index into a [row][64] ushort LDS tile: XOR bits 3..5 of n with row&7
// (keeps 8-ushort groups contiguous -> b128 reads legal; rows spread over banks)
#define SWZ(row, n) ((((row) * 64) + (n)) ^ (((row) & 7) << 3))

__global__ __launch_bounds__(64) void enc_main(
    const float* __restrict__ x,      // [B][C][N]
    const float* __restrict__ cwt2,   // [C][K] = -2*scale[k]*cw[k][c]
    const float* __restrict__ scale,  // [K]
    const float* __restrict__ sc2,    // [K] = scale[k]*||cw_k||^2
    float* __restrict__ wxacc,        // [B][K][C] (zeroed)
    float* __restrict__ wsacc)        // [B][K]    (zeroed)
{
    __shared__ unsigned short xs[C_DIM * TILEN];   // bf16 x[c][n'] swizzled (16 KB)
    __shared__ unsigned short aws[K_DIM * TILEN];  // bf16 aw[k][n'] swizzled (4 KB)

    const int t   = threadIdx.x;     // 0..63 (one wave)
    const int b   = blockIdx.y;
    const int hi  = t >> 5;
    const int l31 = t & 31;

    const float* xb = x + (size_t)b * C_DIM * N_SP;

    f32x16 acc0, acc1, acc2, acc3, accS;
#pragma unroll
    for (int i = 0; i < 16; ++i){
        acc0[i] = 0.f; acc1[i] = 0.f; acc2[i] = 0.f; acc3[i] = 0.f; accS[i] = 0.f;
    }

    short8 ones;
#pragma unroll
    for (int i = 0; i < 8; ++i) ones[i] = (short)0x3F80;  // bf16 1.0

    for (int tile = 0; tile < TILES; ++tile){
        const int n0 = blockIdx.x * (TILES * TILEN) + tile * TILEN;
        __syncthreads();   // xs/aws safe to overwrite (prev tile's MFMA done)

        // ---- phase 1: stream x (R2-proven depth-2 pipeline), fp32 dots, stage bf16 ----
        const float* xp = xb + n0 + t;

        float xc[K_DIM];
#pragma unroll
        for (int k = 0; k < K_DIM; ++k) xc[k] = 0.f;
        float x2 = 0.f;

        float cur[8], nx1[8];
#pragma unroll
        for (int j = 0; j < 8; ++j) cur[j] = xp[j * N_SP];
#pragma unroll
        for (int j = 0; j < 8; ++j) nx1[j] = xp[(8 + j) * N_SP];

#pragma unroll 1
        for (int g = 0; g < 14; ++g){
            float nx2[8];
#pragma unroll
            for (int j = 0; j < 8; ++j)           // issue g+2's loads first
                nx2[j] = xp[((g + 2) * 8 + j) * N_SP];
#pragma unroll
            for (int j = 0; j < 8; ++j){
                const int c = g * 8 + j;
                const float xv = cur[j];
                x2 = fmaf(xv, xv, x2);
                xs[SWZ(c, t)] = f2bf(xv);
                const float* cwc = cwt2 + (c << 5);   // wave-uniform -> s_load
#pragma unroll
                for (int k = 0; k < K_DIM; ++k)
                    xc[k] = fmaf(xv, cwc[k], xc[k]);
            }
#pragma unroll
            for (int j = 0; j < 8; ++j){ cur[j] = nx1[j]; nx1[j] = nx2[j]; }
        }
#pragma unroll
        for (int gg = 14; gg < 16; ++gg){
#pragma unroll
            for (int j = 0; j < 8; ++j){
                const int c = gg * 8 + j;
                const float xv = cur[j];
                x2 = fmaf(xv, xv, x2);
                xs[SWZ(c, t)] = f2bf(xv);
                const float* cwc = cwt2 + (c << 5);
#pragma unroll
                for (int k = 0; k < K_DIM; ++k)
                    xc[k] = fmaf(xv, cwc[k], xc[k]);
            }
#pragma unroll
            for (int j = 0; j < 8; ++j) cur[j] = nx1[j];
        }

        // ---- phase 2: per-thread softmax over k ----
        float m = -3.4e38f;
#pragma unroll
        for (int k = 0; k < K_DIM; ++k){
            float s = fmaf(scale[k], x2, xc[k] + sc2[k]);  // scale*(x2 - 2x.cw + c2)
            xc[k] = s;
            m = fmaxf(m, s);
        }
        float sum = 0.f;
#pragma unroll
        for (int k = 0; k < K_DIM; ++k){
            float p = __expf(xc[k] - m);
            xc[k] = p;
            sum += p;
        }
        float r = 1.f / sum;
#pragma unroll
        for (int k = 0; k < K_DIM; ++k)
            aws[SWZ(k, t)] = f2bf(xc[k] * r);

        __syncthreads();

        // ---- phase 3: wx[k][c] += aw[k][n] * x[n][c] via MFMA (acc across tiles) ----
#pragma unroll
        for (int ks = 0; ks < 4; ++ks){            // Kdim = n = 64 -> 4 steps of 16
            const int n8 = ks * 16 + hi * 8;
            short8 af  = *(const short8*)(const void*)&aws[SWZ(l31, n8)];
            short8 bf0 = *(const short8*)(const void*)&xs[SWZ(l31, n8)];
            short8 bf1 = *(const short8*)(const void*)&xs[SWZ(32 + l31, n8)];
            short8 bf2 = *(const short8*)(const void*)&xs[SWZ(64 + l31, n8)];
            short8 bf3 = *(const short8*)(const void*)&xs[SWZ(96 + l31, n8)];
            acc0 = __builtin_amdgcn_mfma_f32_32x32x16_bf16(af, bf0, acc0, 0, 0, 0);
            acc1 = __builtin_amdgcn_mfma_f32_32x32x16_bf16(af, bf1, acc1, 0, 0, 0);
            acc2 = __builtin_amdgcn_mfma_f32_32x32x16_bf16(af, bf2, acc2, 0, 0, 0);
            acc3 = __builtin_amdgcn_mfma_f32_32x32x16_bf16(af, bf3, acc3, 0, 0, 0);
            accS = __builtin_amdgcn_mfma_f32_32x32x16_bf16(af, ones, accS, 0, 0, 0);
        }
    }

    // ---- epilogue: atomic-reduce block partials to global ----
    float* wxb = wxacc + (size_t)b * K_DIM * C_DIM;
#pragma unroll
    for (int rg = 0; rg < 16; ++rg){
        const int row = (rg & 3) + 8 * (rg >> 2) + 4 * hi;  // verified D layout
        atomicAdd(&wxb[row * C_DIM +      l31], acc0[rg]);
        atomicAdd(&wxb[row * C_DIM + 32 + l31], acc1[rg]);
        atomicAdd(&wxb[row * C_DIM + 64 + l31], acc2[rg]);
        atomicAdd(&wxb[row * C_DIM + 96 + l31], acc3[rg]);
    }
    if (l31 == 0){
#pragma unroll
        for (int rg = 0; rg < 16; ++rg){
            const int row = (rg & 3) + 8 * (rg >> 2) + 4 * hi;
            atomicAdd(&wsacc[b * K_DIM + row], accS[rg]);
        }
    }
}

__global__ void enc_zero(float* __restrict__ p, int n){
    const int i = blockIdx.x * 256 + threadIdx.x;
    if (i < n) p[i] = 0.f;
}

__global__ void enc_prep(const float* __restrict__ cw, const float* __restrict__ scale,
                         float* __restrict__ cwt2, float* __restrict__ sc2){
    const int t = threadIdx.x;  // 128 threads; t = c
    for (int k = 0; k < K_DIM; ++k)
        cwt2[t * K_DIM + k] = -2.f * scale[k] * cw[k * C_DIM + t];
    if (t < K_DIM){
        float s = 0.f;
        for (int c = 0; c < C_DIM; ++c){
            float v = cw[t * C_DIM + c];
            s = fmaf(v, v, s);
        }
        sc2[t] = scale[t] * s;
    }
}

__global__ void enc_final(const float* __restrict__ wxacc, const float* __restrict__ wsacc,
                          const float* __restrict__ cw, float* __restrict__ out){
    const int i  = blockIdx.x * 256 + threadIdx.x;  // B*K*C = 131072
    const int c  = i & (C_DIM - 1);
    const int kk = (i >> 7) & (K_DIM - 1);
    const int bk = i >> 7;
    out[i] = wxacc[i] - wsacc[bk] * cw[kk * C_DIM + c];
}

extern "C" void kernel_launch(void* const* d_in, const int* in_sizes, int n_in,
                              void* d_out, int out_size, void* d_ws, size_t ws_size,
                              hipStream_t stream){
    (void)in_sizes; (void)n_in; (void)out_size; (void)ws_size;
    const float* x     = (const float*)d_in[0];
    const float* cw    = (const float*)d_in[1];
    const float* scale = (const float*)d_in[2];
    float* out = (float*)d_out;

    float* wxacc = (float*)d_ws;                 // 32*32*128 f32
    float* wsacc = wxacc + 32 * 32 * 128;        // 32*32
    float* cwt2  = wsacc + 32 * 32;              // 128*32
    float* sc2   = cwt2 + 128 * 32;              // 32

    const int nz = 32 * 32 * 128 + 32 * 32;
    enc_zero<<<(nz + 255) / 256, 256, 0, stream>>>(wxacc, nz);
    enc_prep<<<1, 128, 0, stream>>>(cw, scale, cwt2, sc2);
    enc_main<<<dim3(NBX, 32), 64, 0, stream>>>(x, cwt2, scale, sc2, wxacc, wsacc);
    enc_final<<<512, 256, 0, stream>>>(wxacc, wsacc, cw, out);
}

// Round 5
// 129.341 us; speedup vs baseline: 1.4762x; 1.1159x over previous
//
#include <hip/hip_runtime.h>

#define N_SP 16384
#define C_DIM 128
#define K_DIM 32
#define NBX   64     // blocks along n
#define TILEN 64     // n per tile
#define TILES 4      // tiles per block; NBX*TILES*TILEN == N_SP

typedef short short8 __attribute__((ext_vector_type(8)));
typedef float f32x16 __attribute__((ext_vector_type(16)));

__device__ __forceinline__ unsigned f2bfu(float f){
    return (__float_as_uint(f) + 0x8000u) >> 16;   // cheap RN to bf16 bits
}
__device__ __forceinline__ unsigned short f2bf(float f){
    return (unsigned short)f2bfu(f);
}

// swizzled index into a [row][64] ushort LDS tile: XOR bits 3..5 of n with row&7
#define SWZ(row, n) ((((row) * 64) + (n)) ^ (((row) & 7) << 3))

union FragU { int i[4]; short8 s; };

__global__ __launch_bounds__(64, 2) void enc_main(
    const float* __restrict__ x,              // [B][C][N]
    const unsigned short* __restrict__ cwt2b, // [K][C] bf16 of -2*scale[k]*cw[k][c]
    const float* __restrict__ combo,          // [K][2] = {scale[k], scale[k]*||cw_k||^2}
    float* __restrict__ wxacc,                // [B][K][C] (zeroed)
    float* __restrict__ wsacc)                // [B][K]    (zeroed)
{
    __shared__ unsigned short xs[C_DIM * TILEN];   // bf16 x[c][n'] swizzled (16 KB)
    __shared__ unsigned short aws[K_DIM * TILEN];  // bf16 aw[k][n'] swizzled (4 KB)

    const int t   = threadIdx.x;   // 0..63, one wave; thread t owns n-column n0+t
    const int b   = blockIdx.y;
    const int hi  = t >> 5;
    const int l31 = t & 31;

    const float* xb = x + (size_t)b * C_DIM * N_SP;

    // held codeword A-fragments: lane l31 = k-row, hi picks 8-c subslice of each 16-chunk
    short8 cwA[8];
#pragma unroll
    for (int ksg = 0; ksg < 8; ++ksg)
        cwA[ksg] = *(const short8*)(const void*)(cwt2b + l31 * C_DIM + ksg * 16 + hi * 8);

    f32x16 acc0, acc1, acc2, acc3, accS;
#pragma unroll
    for (int i = 0; i < 16; ++i){
        acc0[i]=0.f; acc1[i]=0.f; acc2[i]=0.f; acc3[i]=0.f; accS[i]=0.f;
    }
    short8 ones;
#pragma unroll
    for (int i = 0; i < 8; ++i) ones[i] = (short)0x3F80;  // bf16 1.0

    for (int tile = 0; tile < TILES; ++tile){
        const int n0 = blockIdx.x * (TILES * TILEN) + tile * TILEN;
        const float* xp = xb + n0 + t;

        __syncthreads();   // xs/aws safe to overwrite (prev tile's phase-D done)

        f32x16 sA, sB;     // S[k][n] accumulators: group0 cols n=l31, group1 n=32+l31
#pragma unroll
        for (int i = 0; i < 16; ++i){ sA[i]=0.f; sB[i]=0.f; }

        float x2 = 0.f;
        int xr[32];        // packed bf16 of this thread's n-column, current c-half

#pragma unroll
        for (int h = 0; h < 2; ++h){
            const int cb = h * 64;
            // ---- stream 64 c-rows (depth-2, 8-wide), fp32 x2, stage xs, pack xr ----
            float cur[8], nx1[8];
#pragma unroll
            for (int j = 0; j < 8; ++j) cur[j] = xp[(cb + j) * N_SP];
#pragma unroll
            for (int j = 0; j < 8; ++j) nx1[j] = xp[(cb + 8 + j) * N_SP];

#pragma unroll
            for (int g = 0; g < 8; ++g){
                float nx2[8];
                if (g < 6){
#pragma unroll
                    for (int j = 0; j < 8; ++j) nx2[j] = xp[(cb + (g + 2) * 8 + j) * N_SP];
                } else {
#pragma unroll
                    for (int j = 0; j < 8; ++j) nx2[j] = 0.f;
                }
#pragma unroll
                for (int j = 0; j < 8; j += 2){
                    const int cl = g * 8 + j;      // local c in half (0..63)
                    const int c  = cb + cl;
                    const float a0 = cur[j], a1 = cur[j + 1];
                    x2 = fmaf(a0, a0, x2);
                    x2 = fmaf(a1, a1, x2);
                    const unsigned u0 = f2bfu(a0), u1 = f2bfu(a1);
                    xs[SWZ(c,     t)] = (unsigned short)u0;
                    xs[SWZ(c + 1, t)] = (unsigned short)u1;
                    xr[cl >> 1] = (int)(u0 | (u1 << 16));
                }
                if (g < 7){
#pragma unroll
                    for (int j = 0; j < 8; ++j){ cur[j] = nx1[j]; nx1[j] = nx2[j]; }
                }
            }

            // ---- S += cwt2 * x via MFMA; B-frags built from registers via lane-swap ----
#pragma unroll
            for (int kl = 0; kl < 4; ++kl){
                FragU f0, f1;
#pragma unroll
                for (int d = 0; d < 4; ++d){
                    const int L  = xr[kl * 8 + d];        // c = kl*16 + 2d,2d+1
                    const int H  = xr[kl * 8 + 4 + d];    // c = kl*16+8 + 2d,2d+1
                    const int sl = __shfl_xor(L, 32);
                    const int sh = __shfl_xor(H, 32);
                    f0.i[d] = hi ? sh : L;   // col n=l31     : owner thread l31
                    f1.i[d] = hi ? H  : sl;  // col n=32+l31  : owner thread 32+l31
                }
                sA = __builtin_amdgcn_mfma_f32_32x32x16_bf16(cwA[h*4+kl], f0.s, sA, 0,0,0);
                sB = __builtin_amdgcn_mfma_f32_32x32x16_bf16(cwA[h*4+kl], f1.s, sB, 0,0,0);
            }
        }

        // ---- softmax over k on the MFMA D-layout ----
        float csx[16], csy[16];
#pragma unroll
        for (int q = 0; q < 16; ++q){
            const int row = (q & 3) + 8 * (q >> 2) + 4 * hi;
            csx[q] = combo[2 * row];
            csy[q] = combo[2 * row + 1];
        }
        const float x2o  = __shfl_xor(x2, 32);
        const float x2g0 = hi ? x2o : x2;   // x2[n=l31]
        const float x2g1 = hi ? x2 : x2o;   // x2[n=32+l31]

        {   // group 0: cols n = l31
            float arg[16]; float ml = -3.4e38f;
#pragma unroll
            for (int q = 0; q < 16; ++q){
                arg[q] = fmaf(csx[q], x2g0, sA[q] + csy[q]);
                ml = fmaxf(ml, arg[q]);
            }
            const float mm = fmaxf(ml, __shfl_xor(ml, 32));
            float sum = 0.f;
#pragma unroll
            for (int q = 0; q < 16; ++q){ float p = __expf(arg[q] - mm); arg[q] = p; sum += p; }
            sum += __shfl_xor(sum, 32);
            const float r = 1.f / sum;
#pragma unroll
            for (int q = 0; q < 16; ++q){
                const int row = (q & 3) + 8 * (q >> 2) + 4 * hi;
                aws[SWZ(row, l31)] = f2bf(arg[q] * r);
            }
        }
        {   // group 1: cols n = 32 + l31
            float arg[16]; float ml = -3.4e38f;
#pragma unroll
            for (int q = 0; q < 16; ++q){
                arg[q] = fmaf(csx[q], x2g1, sB[q] + csy[q]);
                ml = fmaxf(ml, arg[q]);
            }
            const float mm = fmaxf(ml, __shfl_xor(ml, 32));
            float sum = 0.f;
#pragma unroll
            for (int q = 0; q < 16; ++q){ float p = __expf(arg[q] - mm); arg[q] = p; sum += p; }
            sum += __shfl_xor(sum, 32);
            const float r = 1.f / sum;
#pragma unroll
            for (int q = 0; q < 16; ++q){
                const int row = (q & 3) + 8 * (q >> 2) + 4 * hi;
                aws[SWZ(row, 32 + l31)] = f2bf(arg[q] * r);
            }
        }

        __syncthreads();

        // ---- phase D: wx[k][c] += aw[k][n] * x[n][c] (identical to passing R4) ----
#pragma unroll
        for (int ks = 0; ks < 4; ++ks){
            const int n8 = ks * 16 + hi * 8;
            short8 af  = *(const short8*)(const void*)&aws[SWZ(l31, n8)];
            short8 bf0 = *(const short8*)(const void*)&xs[SWZ(l31,      n8)];
            short8 bf1 = *(const short8*)(const void*)&xs[SWZ(32 + l31, n8)];
            short8 bf2 = *(const short8*)(const void*)&xs[SWZ(64 + l31, n8)];
            short8 bf3 = *(const short8*)(const void*)&xs[SWZ(96 + l31, n8)];
            acc0 = __builtin_amdgcn_mfma_f32_32x32x16_bf16(af, bf0, acc0, 0, 0, 0);
            acc1 = __builtin_amdgcn_mfma_f32_32x32x16_bf16(af, bf1, acc1, 0, 0, 0);
            acc2 = __builtin_amdgcn_mfma_f32_32x32x16_bf16(af, bf2, acc2, 0, 0, 0);
            acc3 = __builtin_amdgcn_mfma_f32_32x32x16_bf16(af, bf3, acc3, 0, 0, 0);
            accS = __builtin_amdgcn_mfma_f32_32x32x16_bf16(af, ones, accS, 0, 0, 0);
        }
    }

    // ---- epilogue: atomic-reduce block partials to global ----
    float* wxb = wxacc + (size_t)b * K_DIM * C_DIM;
#pragma unroll
    for (int rg = 0; rg < 16; ++rg){
        const int row = (rg & 3) + 8 * (rg >> 2) + 4 * hi;  // verified D layout
        atomicAdd(&wxb[row * C_DIM +      l31], acc0[rg]);
        atomicAdd(&wxb[row * C_DIM + 32 + l31], acc1[rg]);
        atomicAdd(&wxb[row * C_DIM + 64 + l31], acc2[rg]);
        atomicAdd(&wxb[row * C_DIM + 96 + l31], acc3[rg]);
    }
    if (l31 == 0){
#pragma unroll
        for (int rg = 0; rg < 16; ++rg){
            const int row = (rg & 3) + 8 * (rg >> 2) + 4 * hi;
            atomicAdd(&wsacc[b * K_DIM + row], accS[rg]);
        }
    }
}

__global__ void enc_zero(float* __restrict__ p, int n){
    const int i = blockIdx.x * 256 + threadIdx.x;
    if (i < n) p[i] = 0.f;
}

__global__ void enc_prep(const float* __restrict__ cw, const float* __restrict__ scale,
                         unsigned short* __restrict__ cwt2b, float* __restrict__ combo){
    const int t = threadIdx.x;  // 128 threads; t = c
    for (int k = 0; k < K_DIM; ++k)
        cwt2b[k * C_DIM + t] = f2bf(-2.f * scale[k] * cw[k * C_DIM + t]);
    if (t < K_DIM){
        float s = 0.f;
        for (int c = 0; c < C_DIM; ++c){
            float v = cw[t * C_DIM + c];
            s = fmaf(v, v, s);
        }
        combo[2 * t]     = scale[t];
        combo[2 * t + 1] = scale[t] * s;
    }
}

__global__ void enc_final(const float* __restrict__ wxacc, const float* __restrict__ wsacc,
                          const float* __restrict__ cw, float* __restrict__ out){
    const int i  = blockIdx.x * 256 + threadIdx.x;  // B*K*C = 131072
    const int c  = i & (C_DIM - 1);
    const int kk = (i >> 7) & (K_DIM - 1);
    const int bk = i >> 7;
    out[i] = wxacc[i] - wsacc[bk] * cw[kk * C_DIM + c];
}

extern "C" void kernel_launch(void* const* d_in, const int* in_sizes, int n_in,
                              void* d_out, int out_size, void* d_ws, size_t ws_size,
                              hipStream_t stream){
    (void)in_sizes; (void)n_in; (void)out_size; (void)ws_size;
    const float* x     = (const float*)d_in[0];
    const float* cw    = (const float*)d_in[1];
    const float* scale = (const float*)d_in[2];
    float* out = (float*)d_out;

    float* wxacc = (float*)d_ws;                         // 131072 f
    float* wsacc = wxacc + K_DIM * K_DIM * C_DIM;        // wait: B*K = 32*32 = 1024 f
    float* combo = wsacc + 32 * 32;                      // 64 f
    unsigned short* cwt2b = (unsigned short*)(combo + 64);  // 4096 ushort

    const int nz = 32 * 32 * 128 + 32 * 32;
    enc_zero<<<(nz + 255) / 256, 256, 0, stream>>>(wxacc, nz);
    enc_prep<<<1, 128, 0, stream>>>(cw, scale, cwt2b, combo);
    enc_main<<<dim3(NBX, 32), 64, 0, stream>>>(x, cwt2b, combo, wxacc, wsacc);
    enc_final<<<512, 256, 0, stream>>>(wxacc, wsacc, cw, out);
}